// Round 8
// baseline (1015.417 us; speedup 1.0000x reference)
//
#include <hip/hip_runtime.h>
#include <hip/hip_bf16.h>
#include <math.h>

typedef __attribute__((ext_vector_type(8))) short short8;
typedef __attribute__((ext_vector_type(4))) short short4v;
typedef __attribute__((ext_vector_type(4))) float floatx4;
typedef unsigned short ushort_t;
typedef unsigned int uint_t;

__device__ __forceinline__ ushort_t f2bf(float x) {   // RNE f32 -> bf16
    uint_t u = __float_as_uint(x);
    uint_t r = (u + 0x7fffu + ((u >> 16) & 1u)) >> 16;
    return (ushort_t)r;
}
// HW-packed RNE conversion: 2 floats -> packed bf16x2 (v_cvt_pk_bf16_f32)
__device__ __forceinline__ short4v pack4(float a, float b, float c, float d) {
    union { __hip_bfloat162 h; uint_t u; } lo, hi;
    lo.h = __float22bfloat162_rn(make_float2(a, b));
    hi.h = __float22bfloat162_rn(make_float2(c, d));
    short4v r;
    r[0] = (short)(lo.u & 0xffffu); r[1] = (short)(lo.u >> 16);
    r[2] = (short)(hi.u & 0xffffu); r[3] = (short)(hi.u >> 16);
    return r;
}
__device__ __forceinline__ short8 pack8(float4 v0, float4 v1) {
    short4v lo = pack4(v0.x, v0.y, v0.z, v0.w);
    short4v hi = pack4(v1.x, v1.y, v1.z, v1.w);
    short8 pk;
    pk[0] = lo[0]; pk[1] = lo[1]; pk[2] = lo[2]; pk[3] = lo[3];
    pk[4] = hi[0]; pk[5] = hi[1]; pk[6] = hi[2]; pk[7] = hi[3];
    return pk;
}

// ---------------- prep: weight tiling (W1/W2/W3) + partial GAP -------------
// blocks [0,432): W1/W2 bf16 MFMA tiles [tap][ci/8][64 co][8 ci]
// blocks [432,648): W3 tiles [branch][cls][18 t2][4 q][16 ch][8 j] (ch>=NCH -> 0)
// blocks [648,680): GAP partials
__global__ void prep_all(const float* __restrict__ W1a, const float* __restrict__ W2a,
                         const float* __restrict__ W1b, const float* __restrict__ W2b,
                         const float* __restrict__ W3a, const float* __restrict__ W3b,
                         ushort_t* __restrict__ wt, ushort_t* __restrict__ w3t,
                         const float* __restrict__ f4, float* __restrict__ part) {
    __shared__ float4 red[256];
    int bi = blockIdx.x, t = threadIdx.x;
    if (bi < 432) {
        int i = bi * 256 + t;
        const float* W; int off; int C;
        if (i < 18432)      { W = W1a; off = i;         C = 32; }
        else if (i < 55296) { W = W2a; off = i - 18432; C = 64; }
        else if (i < 73728) { W = W1b; off = i - 55296; C = 32; }
        else                { W = W2b; off = i - 73728; C = 64; }
        int pt = C * 64;
        int tap = off / pt, rem = off - tap * pt;
        int k4 = rem >> 9, rem2 = rem & 511;
        int co = rem2 >> 3, j = rem2 & 7;
        int ci = k4 * 8 + j;
        wt[i] = f2bf(W[(size_t)(tap * C + ci) * 64 + co]);
    } else if (bi < 648) {
        int i = (bi - 432) * 256 + t;          // [0, 55296)
        int branch = i / 27648; int r = i - branch * 27648;
        int cls = r / 9216; int r2 = r - cls * 9216;
        int t2 = r2 >> 9; int r3 = r2 & 511;
        int qq = r3 >> 7; int r4 = r3 & 127;
        int ch = r4 >> 3; int j = r4 & 7;
        int tap = t2 >> 1, kh = t2 & 1;
        int ci = kh * 32 + qq * 8 + j;
        int NCH = branch ? 1 : 2, C3 = branch ? 3 : 6;
        const float* W3 = branch ? W3b : W3a;
        ushort_t v = 0;
        if (ch < NCH) v = f2bf(W3[(size_t)(tap * 64 + ci) * C3 + cls * NCH + ch]);
        w3t[i] = v;
    } else {
        int g = bi - 648;
        int c = g & 7, b = g >> 3;
        int ci4 = t & 63, po = t >> 6;
        const float* f = f4 + ((size_t)b * 1024 + c * 128) * 256;
        float4 s = {0, 0, 0, 0};
        for (int i = 0; i < 32; ++i) {
            float4 v = *(const float4*)&f[(size_t)(i * 4 + po) * 256 + ci4 * 4];
            s.x += v.x; s.y += v.y; s.z += v.z; s.w += v.w;
        }
        red[t] = s;
        __syncthreads();
        if (t < 64) {
            float4 a = red[t], b2 = red[64 + t], c2 = red[128 + t], d2 = red[192 + t];
            float4 gg;
            gg.x = a.x + b2.x + c2.x + d2.x;
            gg.y = a.y + b2.y + c2.y + d2.y;
            gg.z = a.z + b2.z + c2.z + d2.z;
            gg.w = a.w + b2.w + c2.w + d2.w;
            *(float4*)&part[((b * 8 + c) << 8) + t * 4] = gg;
        }
    }
}

// ---------------- classifier finish: MLP + softmax + argmax ----------------
__global__ void cls_finish(const float* __restrict__ part,
                           const float* __restrict__ Wc1, const float* __restrict__ bc1,
                           const float* __restrict__ Wc2, const float* __restrict__ bc2,
                           const float* __restrict__ Wc3, const float* __restrict__ bc3,
                           float* __restrict__ pred_out, int* __restrict__ cls_out) {
    int b = blockIdx.x;
    int t = threadIdx.x;                       // 256 threads
    __shared__ float gap[256];
    __shared__ float z1[128];
    __shared__ float z2[128];
    __shared__ float lg[3];
    float s = 0.f;
    for (int c = 0; c < 8; ++c) s += part[((b * 8 + c) << 8) + t];
    gap[t] = s * (1.0f / 1024.0f);
    __syncthreads();
    if (t < 128) {
        float a = bc1[t];
        for (int i = 0; i < 256; ++i) a += gap[i] * Wc1[i * 128 + t];
        z1[t] = fmaxf(a, 0.f);
    }
    __syncthreads();
    if (t < 128) {
        float a = bc2[t];
        for (int i = 0; i < 128; ++i) a += z1[i] * Wc2[i * 128 + t];
        z2[t] = fmaxf(a, 0.f);
    }
    __syncthreads();
    if (t < 3) {
        float a = bc3[t];
        for (int i = 0; i < 128; ++i) a += z2[i] * Wc3[i * 3 + t];
        lg[t] = a;
    }
    __syncthreads();
    if (t == 0) {
        float m = fmaxf(lg[0], fmaxf(lg[1], lg[2]));
        float e0 = expf(lg[0] - m), e1 = expf(lg[1] - m), e2 = expf(lg[2] - m);
        float ssum = e0 + e1 + e2;
        pred_out[b * 3 + 0] = e0 / ssum;
        pred_out[b * 3 + 1] = e1 / ssum;
        pred_out[b * 3 + 2] = e2 / ssum;
        int idx = 0; float best = lg[0];
        if (lg[1] > best) { best = lg[1]; idx = 1; }
        if (lg[2] > best) { best = lg[2]; idx = 2; }
        cls_out[b] = idx;
    }
}

// ---------------- fused conv kernel: BOTH branches per block ---------------
// x0 staged once (bf16); branch-o then branch-w run sequentially.
// A = weights from global (pre-tiled); B = pixels in LDS.
// LDS (ushort), padded ks strides (q-phases land 8-24 banks apart):
//   x0  [4 ks x 2608]   : [0, 10432)
//   h1  [8 ks x 2064]   : [10432, 26944)
//   h2  [8 ks x 1616]   : overlays h1 region (reads drained by barrier)
// Total 53888 B -> 3 blocks/CU.
#define X0_E 0
#define X0_KS 2608
#define H1_E 10432
#define H1_KS 2064
#define H2_KS 1616
#define LDS_E 26944

__global__ __launch_bounds__(256, 3)
void fused_branch(const float* __restrict__ x0,
                  const ushort_t* __restrict__ W1o_t, const ushort_t* __restrict__ W2o_t,
                  const ushort_t* __restrict__ W1w_t, const ushort_t* __restrict__ W2w_t,
                  const ushort_t* __restrict__ w3t,
                  const float* __restrict__ bo1, const float* __restrict__ bo2,
                  const float* __restrict__ bw1, const float* __restrict__ bw2,
                  const float* __restrict__ bo3, const float* __restrict__ bw3,
                  const int* __restrict__ clsp,
                  float* __restrict__ off_out, float* __restrict__ w_out) {
    __shared__ __align__(16) ushort_t lds[LDS_E];
    const int t = threadIdx.x;
    const int b = blockIdx.y;
    const int tileY = blockIdx.x / 43, tileX = blockIdx.x - tileY * 43;
    const int ty0 = tileY * 12, tx0 = tileX * 12;
    const bool edge = (tileY == 0) | (tileY == 42) | (tileX == 0) | (tileX == 42);
    const int lane = t & 63, wave = t >> 6;
    const int m = lane & 15, q = lane >> 4;
    const int cls = clsp[b];

    // ---- stage x0 once (18x18x32 fp32 -> bf16 [4 ks][324 px][8]) ----
    if (!edge) {
        for (int idx = t; idx < 1296; idx += 256) {
            int pix = idx >> 2, qq = idx & 3;
            int py = pix / 18, px = pix - py * 18;
            const float* xp = x0 + (((size_t)b * 512 + (ty0 - 3 + py)) * 512 + (tx0 - 3 + px)) * 32 + qq * 8;
            *(short8*)&lds[X0_E + qq * X0_KS + pix * 8] =
                pack8(*(const float4*)xp, *(const float4*)(xp + 4));
        }
    } else {
        for (int idx = t; idx < 1296; idx += 256) {
            int pix = idx >> 2, qq = idx & 3;
            int py = pix / 18, px = pix - py * 18;
            int gy = ty0 - 3 + py, gx = tx0 - 3 + px;
            float4 v0 = {0, 0, 0, 0}, v1 = {0, 0, 0, 0};
            if ((uint_t)gy < 512u && (uint_t)gx < 512u) {
                const float* xp = x0 + (((size_t)b * 512 + gy) * 512 + gx) * 32 + qq * 8;
                v0 = *(const float4*)xp;
                v1 = *(const float4*)(xp + 4);
            }
            *(short8*)&lds[X0_E + qq * X0_KS + pix * 8] = pack8(v0, v1);
        }
    }
    __syncthreads();

#pragma unroll
    for (int br = 0; br < 2; ++br) {
        const ushort_t* W1t = br ? W1w_t : W1o_t;
        const ushort_t* W2t = br ? W2w_t : W2o_t;
        const ushort_t* W3T = w3t + br * 27648;
        const float* B1 = br ? bw1 : bo1;
        const float* B2 = br ? bw2 : bo2;
        const float* B3 = br ? bw3 : bo3;
        float* outp = br ? w_out : off_out;
        const int NCH = br ? 1 : 2;

        // ================= conv1: h1(16x16x64), A from global ==============
        {
            floatx4 acc[4][4];
#pragma unroll
            for (int mi = 0; mi < 4; ++mi) {
                float4 bb = *(const float4*)&B1[mi * 16 + q * 4];
                floatx4 ib = (floatx4){bb.x, bb.y, bb.z, bb.w};
#pragma unroll
                for (int n = 0; n < 4; ++n) acc[mi][n] = ib;
            }
            const int wsel = q * 512 + m * 8;
            short8 Anow[4];
#pragma unroll
            for (int mi = 0; mi < 4; ++mi)
                Anow[mi] = *(const short8*)&W1t[wsel + mi * 128];

            for (int tap = 0; tap < 9; ++tap) {
                int tn = tap < 8 ? tap + 1 : 8;
                short8 Anext[4];
#pragma unroll
                for (int mi = 0; mi < 4; ++mi)
                    Anext[mi] = *(const short8*)&W1t[tn * 2048 + wsel + mi * 128];
                int dy = tap / 3, dx = tap - dy * 3;
                short8 Bx[4];
#pragma unroll
                for (int n = 0; n < 4; ++n) {
                    int ptile = n * 4 + wave;
                    Bx[n] = *(const short8*)&lds[X0_E + q * X0_KS + ((ptile + dy) * 18 + (m + dx)) * 8];
                }
#pragma unroll
                for (int mi = 0; mi < 4; ++mi)
#pragma unroll
                    for (int n = 0; n < 4; ++n)
                        acc[mi][n] = __builtin_amdgcn_mfma_f32_16x16x32_bf16(Anow[mi], Bx[n], acc[mi][n], 0, 0, 0);
#pragma unroll
                for (int mi = 0; mi < 4; ++mi) Anow[mi] = Anext[mi];
            }
            // epilogue: relu (+mask on edge) -> h1 [8 ks x 2064]
            if (!edge) {
#pragma unroll
                for (int mi = 0; mi < 4; ++mi) {
                    int ks = mi * 2 + (q >> 1), lo = (q & 1) * 4;
#pragma unroll
                    for (int n = 0; n < 4; ++n) {
                        int ptile = n * 4 + wave;
                        floatx4 a = acc[mi][n];
                        *(short4v*)&lds[H1_E + ks * H1_KS + (ptile * 16 + m) * 8 + lo] =
                            pack4(fmaxf(a[0], 0.f), fmaxf(a[1], 0.f), fmaxf(a[2], 0.f), fmaxf(a[3], 0.f));
                    }
                }
            } else {
#pragma unroll
                for (int mi = 0; mi < 4; ++mi) {
                    int ks = mi * 2 + (q >> 1), lo = (q & 1) * 4;
#pragma unroll
                    for (int n = 0; n < 4; ++n) {
                        int ptile = n * 4 + wave;
                        int gy = ty0 - 2 + ptile, gx = tx0 - 2 + m;
                        bool ok = ((uint_t)gy < 512u) && ((uint_t)gx < 512u);
                        floatx4 a = acc[mi][n];
                        float v0 = ok ? fmaxf(a[0], 0.f) : 0.f;
                        float v1 = ok ? fmaxf(a[1], 0.f) : 0.f;
                        float v2 = ok ? fmaxf(a[2], 0.f) : 0.f;
                        float v3 = ok ? fmaxf(a[3], 0.f) : 0.f;
                        *(short4v*)&lds[H1_E + ks * H1_KS + (ptile * 16 + m) * 8 + lo] = pack4(v0, v1, v2, v3);
                    }
                }
            }
        }
        __syncthreads();                               // h1 ready

        // ================= conv2: h2(14x14x64), A from global ==============
        {
            floatx4 acc[4][4];
#pragma unroll
            for (int mi = 0; mi < 4; ++mi) {
                float4 bb = *(const float4*)&B2[mi * 16 + q * 4];
                floatx4 ib = (floatx4){bb.x, bb.y, bb.z, bb.w};
#pragma unroll
                for (int n = 0; n < 4; ++n) acc[mi][n] = ib;
            }
            int hb2[4];
#pragma unroll
            for (int n = 0; n < 4; ++n) {
                int p0 = (n * 4 + wave) * 16 + m;
                int pv = p0 < 196 ? p0 : 195;
                int py = pv / 14, px = pv - py * 14;
                hb2[n] = py * 16 + px;
            }
            const int wsel = q * 512 + m * 8;
            short8 Anow[4];
#pragma unroll
            for (int mi = 0; mi < 4; ++mi)
                Anow[mi] = *(const short8*)&W2t[wsel + mi * 128];

            for (int s = 0; s < 18; ++s) {
                int tap = s >> 1, kh = s & 1;
                int sn = s < 17 ? s + 1 : 17;
                short8 Anext[4];
#pragma unroll
                for (int mi = 0; mi < 4; ++mi)
                    Anext[mi] = *(const short8*)&W2t[(sn >> 1) * 4096 + ((sn & 1) * 4) * 512 + wsel + mi * 128];
                int dy = tap / 3, dx = tap - dy * 3;
                short8 Bx[4];
#pragma unroll
                for (int n = 0; n < 4; ++n)
                    Bx[n] = *(const short8*)&lds[H1_E + (kh * 4 + q) * H1_KS + (hb2[n] + dy * 16 + dx) * 8];
#pragma unroll
                for (int mi = 0; mi < 4; ++mi)
#pragma unroll
                    for (int n = 0; n < 4; ++n) {
                        int ptile = n * 4 + wave;
                        if (ptile < 13)
                            acc[mi][n] = __builtin_amdgcn_mfma_f32_16x16x32_bf16(Anow[mi], Bx[n], acc[mi][n], 0, 0, 0);
                    }
#pragma unroll
                for (int mi = 0; mi < 4; ++mi) Anow[mi] = Anext[mi];
            }
            __syncthreads();                           // drain h1 reads (h2 overlays h1)
            // epilogue: relu (+mask on edge) -> h2 [8 ks x 1616]
#pragma unroll
            for (int n = 0; n < 4; ++n) {
                int ptile = n * 4 + wave;
                if (ptile >= 13) continue;
                int p = ptile * 16 + m;
                bool pok = p < 196;
                bool ok = pok;
                if (edge) {
                    int py = p / 14, px = p - py * 14;
                    int gy = ty0 - 1 + py, gx = tx0 - 1 + px;
                    ok = pok && ((uint_t)gy < 512u) && ((uint_t)gx < 512u);
                }
#pragma unroll
                for (int mi = 0; mi < 4; ++mi) {
                    int ks = mi * 2 + (q >> 1), lo = (q & 1) * 4;
                    floatx4 a = acc[mi][n];
                    float v0 = ok ? fmaxf(a[0], 0.f) : 0.f;
                    float v1 = ok ? fmaxf(a[1], 0.f) : 0.f;
                    float v2 = ok ? fmaxf(a[2], 0.f) : 0.f;
                    float v3 = ok ? fmaxf(a[3], 0.f) : 0.f;
                    if (pok)
                        *(short4v*)&lds[H1_E + ks * H2_KS + p * 8 + lo] = pack4(v0, v1, v2, v3);
                }
            }
        }
        __syncthreads();                               // h2 ready

        // ========== conv3 via MFMA: wave owns n in {wave, wave+4, wave+8} ==
        {
            floatx4 acc3[3];
#pragma unroll
            for (int j = 0; j < 3; ++j) acc3[j] = (floatx4){0.f, 0.f, 0.f, 0.f};
            int hb3[3];
#pragma unroll
            for (int j = 0; j < 3; ++j) {
                int n = wave + 4 * j;
                int p = (n < 9 ? n : 8) * 16 + m;
                int pv = p < 144 ? p : 143;
                int py = pv / 12, px = pv - py * 12;
                hb3[j] = py * 14 + px;
            }
            const ushort_t* W3c = W3T + cls * 9216;
            for (int t2 = 0; t2 < 18; ++t2) {
                int tap = t2 >> 1, kh = t2 & 1;
                int dy = tap / 3, dx = tap - dy * 3;
                short8 Aw = *(const short8*)&W3c[t2 * 512 + q * 128 + m * 8];
#pragma unroll
                for (int j = 0; j < 3; ++j) {
                    if (wave + 4 * j < 9) {
                        short8 Bh = *(const short8*)&lds[H1_E + (kh * 4 + q) * H2_KS + (hb3[j] + dy * 14 + dx) * 8];
                        acc3[j] = __builtin_amdgcn_mfma_f32_16x16x32_bf16(Aw, Bh, acc3[j], 0, 0, 0);
                    }
                }
            }
            // direct write: C rows 0..NCH-1 live in q==0 lanes, regs 0..NCH-1
            if (q == 0) {
#pragma unroll
                for (int j = 0; j < 3; ++j) {
                    int n = wave + 4 * j;
                    if (n < 9) {
                        int p = n * 16 + m;
                        if (p < 144) {
                            int py = p / 12, px = p - py * 12;
                            int gy = ty0 + py, gx = tx0 + px;
                            if (((uint_t)gy < 512u) && ((uint_t)gx < 512u)) {
                                size_t ob = (((size_t)b * 512 + gy) * 512 + gx) * NCH;
                                outp[ob] = acc3[j][0] + B3[cls * NCH + 0];
                                if (NCH == 2) outp[ob + 1] = acc3[j][1] + B3[cls * NCH + 1];
                            }
                        }
                    }
                }
            }
        }
        if (br == 0) __syncthreads();                  // drain h2 reads before h1w writes
    }
}

extern "C" void kernel_launch(void* const* d_in, const int* in_sizes, int n_in,
                              void* d_out, int out_size, void* d_ws, size_t ws_size,
                              hipStream_t stream) {
    const float* x0  = (const float*)d_in[0];
    const float* f4  = (const float*)d_in[1];
    const float* Wo1 = (const float*)d_in[2];  const float* bo1 = (const float*)d_in[3];
    const float* Wo2 = (const float*)d_in[4];  const float* bo2 = (const float*)d_in[5];
    const float* Wo3 = (const float*)d_in[6];  const float* bo3 = (const float*)d_in[7];
    const float* Ww1 = (const float*)d_in[8];  const float* bw1 = (const float*)d_in[9];
    const float* Ww2 = (const float*)d_in[10]; const float* bw2 = (const float*)d_in[11];
    const float* Ww3 = (const float*)d_in[12]; const float* bw3 = (const float*)d_in[13];
    const float* Wc1 = (const float*)d_in[14]; const float* bc1 = (const float*)d_in[15];
    const float* Wc2 = (const float*)d_in[16]; const float* bc2 = (const float*)d_in[17];
    const float* Wc3 = (const float*)d_in[18]; const float* bc3 = (const float*)d_in[19];

    float* out = (float*)d_out;
    float* offsets_out = out;                      // (4,512,512,2)
    float* weights_out = out + 2097152;            // (4,512,512,1)
    float* pred_out    = out + 3145728;            // (4,3)

    int* cls_ws = (int*)d_ws;                              // 16 B
    ushort_t* wt  = (ushort_t*)((char*)d_ws + 16);         // 110592 ushorts
    ushort_t* w3t = (ushort_t*)((char*)d_ws + 221200);     // 2x27648 ushorts
    float* gap_part = (float*)((char*)d_ws + 331792);      // 4x8x256 floats

    const ushort_t* W1o_t = wt;
    const ushort_t* W2o_t = wt + 18432;
    const ushort_t* W1w_t = wt + 55296;
    const ushort_t* W2w_t = wt + 73728;

    prep_all<<<680, 256, 0, stream>>>(Wo1, Wo2, Ww1, Ww2, Wo3, Ww3, wt, w3t, f4, gap_part);
    cls_finish<<<4, 256, 0, stream>>>(gap_part, Wc1, bc1, Wc2, bc2, Wc3, bc3, pred_out, cls_ws);

    dim3 grid(43 * 43, 4);
    fused_branch<<<grid, 256, 0, stream>>>(x0,
                                           W1o_t, W2o_t, W1w_t, W2w_t, w3t,
                                           bo1, bo2, bw1, bw2,
                                           bo3, bw3,
                                           cls_ws, offsets_out, weights_out);
}

// Round 9
// 723.582 us; speedup vs baseline: 1.4033x; 1.4033x over previous
//
#include <hip/hip_runtime.h>
#include <hip/hip_bf16.h>
#include <math.h>

typedef __attribute__((ext_vector_type(8))) short short8;
typedef __attribute__((ext_vector_type(4))) short short4v;
typedef __attribute__((ext_vector_type(4))) float floatx4;
typedef unsigned short ushort_t;
typedef unsigned int uint_t;

__device__ __forceinline__ ushort_t f2bf(float x) {   // RNE f32 -> bf16
    uint_t u = __float_as_uint(x);
    uint_t r = (u + 0x7fffu + ((u >> 16) & 1u)) >> 16;
    return (ushort_t)r;
}
// HW-packed RNE conversion: 2 floats -> packed bf16x2 (v_cvt_pk_bf16_f32)
__device__ __forceinline__ short4v pack4(float a, float b, float c, float d) {
    union { __hip_bfloat162 h; uint_t u; } lo, hi;
    lo.h = __float22bfloat162_rn(make_float2(a, b));
    hi.h = __float22bfloat162_rn(make_float2(c, d));
    short4v r;
    r[0] = (short)(lo.u & 0xffffu); r[1] = (short)(lo.u >> 16);
    r[2] = (short)(hi.u & 0xffffu); r[3] = (short)(hi.u >> 16);
    return r;
}
__device__ __forceinline__ short8 pack8(float4 v0, float4 v1) {
    short4v lo = pack4(v0.x, v0.y, v0.z, v0.w);
    short4v hi = pack4(v1.x, v1.y, v1.z, v1.w);
    short8 pk;
    pk[0] = lo[0]; pk[1] = lo[1]; pk[2] = lo[2]; pk[3] = lo[3];
    pk[4] = hi[0]; pk[5] = hi[1]; pk[6] = hi[2]; pk[7] = hi[3];
    return pk;
}

// ---------------- prep: weight tiling (W1/W2/W3) + partial GAP -------------
// blocks [0,432): W1/W2 bf16 MFMA tiles [tap][ci/8][64 co][8 ci]
// blocks [432,648): W3 tiles [branch][cls][18 t2][4 q][16 ch][8 j] (ch>=NCH -> 0)
// blocks [648,680): GAP partials
__global__ void prep_all(const float* __restrict__ W1a, const float* __restrict__ W2a,
                         const float* __restrict__ W1b, const float* __restrict__ W2b,
                         const float* __restrict__ W3a, const float* __restrict__ W3b,
                         ushort_t* __restrict__ wt, ushort_t* __restrict__ w3t,
                         const float* __restrict__ f4, float* __restrict__ part) {
    __shared__ float4 red[256];
    int bi = blockIdx.x, t = threadIdx.x;
    if (bi < 432) {
        int i = bi * 256 + t;
        const float* W; int off; int C;
        if (i < 18432)      { W = W1a; off = i;         C = 32; }
        else if (i < 55296) { W = W2a; off = i - 18432; C = 64; }
        else if (i < 73728) { W = W1b; off = i - 55296; C = 32; }
        else                { W = W2b; off = i - 73728; C = 64; }
        int pt = C * 64;
        int tap = off / pt, rem = off - tap * pt;
        int k4 = rem >> 9, rem2 = rem & 511;
        int co = rem2 >> 3, j = rem2 & 7;
        int ci = k4 * 8 + j;
        wt[i] = f2bf(W[(size_t)(tap * C + ci) * 64 + co]);
    } else if (bi < 648) {
        int i = (bi - 432) * 256 + t;          // [0, 55296)
        int branch = i / 27648; int r = i - branch * 27648;
        int cls = r / 9216; int r2 = r - cls * 9216;
        int t2 = r2 >> 9; int r3 = r2 & 511;
        int qq = r3 >> 7; int r4 = r3 & 127;
        int ch = r4 >> 3; int j = r4 & 7;
        int tap = t2 >> 1, kh = t2 & 1;
        int ci = kh * 32 + qq * 8 + j;
        int NCH = branch ? 1 : 2, C3 = branch ? 3 : 6;
        const float* W3 = branch ? W3b : W3a;
        ushort_t v = 0;
        if (ch < NCH) v = f2bf(W3[(size_t)(tap * 64 + ci) * C3 + cls * NCH + ch]);
        w3t[i] = v;
    } else {
        int g = bi - 648;
        int c = g & 7, b = g >> 3;
        int ci4 = t & 63, po = t >> 6;
        const float* f = f4 + ((size_t)b * 1024 + c * 128) * 256;
        float4 s = {0, 0, 0, 0};
        for (int i = 0; i < 32; ++i) {
            float4 v = *(const float4*)&f[(size_t)(i * 4 + po) * 256 + ci4 * 4];
            s.x += v.x; s.y += v.y; s.z += v.z; s.w += v.w;
        }
        red[t] = s;
        __syncthreads();
        if (t < 64) {
            float4 a = red[t], b2 = red[64 + t], c2 = red[128 + t], d2 = red[192 + t];
            float4 gg;
            gg.x = a.x + b2.x + c2.x + d2.x;
            gg.y = a.y + b2.y + c2.y + d2.y;
            gg.z = a.z + b2.z + c2.z + d2.z;
            gg.w = a.w + b2.w + c2.w + d2.w;
            *(float4*)&part[((b * 8 + c) << 8) + t * 4] = gg;
        }
    }
}

// ---------------- classifier finish: MLP + softmax + argmax ----------------
__global__ void cls_finish(const float* __restrict__ part,
                           const float* __restrict__ Wc1, const float* __restrict__ bc1,
                           const float* __restrict__ Wc2, const float* __restrict__ bc2,
                           const float* __restrict__ Wc3, const float* __restrict__ bc3,
                           float* __restrict__ pred_out, int* __restrict__ cls_out) {
    int b = blockIdx.x;
    int t = threadIdx.x;                       // 256 threads
    __shared__ float gap[256];
    __shared__ float z1[128];
    __shared__ float z2[128];
    __shared__ float lg[3];
    float s = 0.f;
    for (int c = 0; c < 8; ++c) s += part[((b * 8 + c) << 8) + t];
    gap[t] = s * (1.0f / 1024.0f);
    __syncthreads();
    if (t < 128) {
        float a = bc1[t];
        for (int i = 0; i < 256; ++i) a += gap[i] * Wc1[i * 128 + t];
        z1[t] = fmaxf(a, 0.f);
    }
    __syncthreads();
    if (t < 128) {
        float a = bc2[t];
        for (int i = 0; i < 128; ++i) a += z1[i] * Wc2[i * 128 + t];
        z2[t] = fmaxf(a, 0.f);
    }
    __syncthreads();
    if (t < 3) {
        float a = bc3[t];
        for (int i = 0; i < 128; ++i) a += z2[i] * Wc3[i * 3 + t];
        lg[t] = a;
    }
    __syncthreads();
    if (t == 0) {
        float m = fmaxf(lg[0], fmaxf(lg[1], lg[2]));
        float e0 = expf(lg[0] - m), e1 = expf(lg[1] - m), e2 = expf(lg[2] - m);
        float ssum = e0 + e1 + e2;
        pred_out[b * 3 + 0] = e0 / ssum;
        pred_out[b * 3 + 1] = e1 / ssum;
        pred_out[b * 3 + 2] = e2 / ssum;
        int idx = 0; float best = lg[0];
        if (lg[1] > best) { best = lg[1]; idx = 1; }
        if (lg[2] > best) { best = lg[2]; idx = 2; }
        cls_out[b] = idx;
    }
}

// ---------------- fused MFMA conv branch (R7 structure + stride fixes) -----
// z (branch) folded into blockIdx.x so blocks i and i+8 share a tile on the
// SAME XCD (round-robin i%8) -> second x0 fetch hits L2.
// A = weights from global (pre-tiled); B = pixels in LDS.
// LDS (ushort), all ks strides give q-phases banks {0,8,16,24}:
//   x0  [4 ks x 2608]   : [0, 10432)
//   h1  [8 ks x 2064]   : [10432, 26944)
//   h2  [8 ks x 1616]   : [0, 12928)      overlays x0+h1-head (post-barrier)
//   SF  1152 floats     : floats [7200, 8352) = ushort [14400, 16704)
// Total 53888 B -> 3 blocks/CU.
#define X0_E 0
#define X0_KS 2608
#define H1_E 10432
#define H1_KS 2064
#define H2_E 0
#define H2_KS 1616
#define SF_F 7200
#define LDS_E 26944

__global__ __launch_bounds__(256, 3)
void fused_branch(const float* __restrict__ x0,
                  const ushort_t* __restrict__ W1o_t, const ushort_t* __restrict__ W2o_t,
                  const ushort_t* __restrict__ W1w_t, const ushort_t* __restrict__ W2w_t,
                  const ushort_t* __restrict__ w3t,
                  const float* __restrict__ bo1, const float* __restrict__ bo2,
                  const float* __restrict__ bw1, const float* __restrict__ bw2,
                  const float* __restrict__ bo3, const float* __restrict__ bw3,
                  const int* __restrict__ clsp,
                  float* __restrict__ off_out, float* __restrict__ w_out) {
    __shared__ __align__(16) ushort_t lds[LDS_E];
    float* ldsf = (float*)lds;
    const int t = threadIdx.x;
    const int b = blockIdx.y;
    // pair mapping: chunk of 16 blocks covers 8 tiles x 2 z on one XCD pass
    const int u = blockIdx.x;
    const int slot = u & 15;
    const int z = slot >> 3;
    const int tix = (u >> 4) * 8 + (slot & 7);
    if (tix >= 1849) return;
    const ushort_t* W1t = z ? W1w_t : W1o_t;
    const ushort_t* W2t = z ? W2w_t : W2o_t;
    const ushort_t* W3T = w3t + z * 27648;
    const float* B1 = z ? bw1 : bo1;
    const float* B2 = z ? bw2 : bo2;
    const float* B3 = z ? bw3 : bo3;
    float* outp = z ? w_out : off_out;
    const int NCH = z ? 1 : 2;

    const int tileY = tix / 43, tileX = tix - tileY * 43;
    const int ty0 = tileY * 12, tx0 = tileX * 12;
    const bool edge = (tileY == 0) | (tileY == 42) | (tileX == 0) | (tileX == 42);
    const int lane = t & 63, wave = t >> 6;
    const int m = lane & 15, q = lane >> 4;
    const int cls = clsp[b];

    // ---- stage x0 (18x18x32 fp32 -> bf16 [4 ks][324 px][8]) ----
    if (!edge) {
        for (int idx = t; idx < 1296; idx += 256) {
            int pix = idx >> 2, qq = idx & 3;
            int py = pix / 18, px = pix - py * 18;
            const float* xp = x0 + (((size_t)b * 512 + (ty0 - 3 + py)) * 512 + (tx0 - 3 + px)) * 32 + qq * 8;
            *(short8*)&lds[X0_E + qq * X0_KS + pix * 8] =
                pack8(*(const float4*)xp, *(const float4*)(xp + 4));
        }
    } else {
        for (int idx = t; idx < 1296; idx += 256) {
            int pix = idx >> 2, qq = idx & 3;
            int py = pix / 18, px = pix - py * 18;
            int gy = ty0 - 3 + py, gx = tx0 - 3 + px;
            float4 v0 = {0, 0, 0, 0}, v1 = {0, 0, 0, 0};
            if ((uint_t)gy < 512u && (uint_t)gx < 512u) {
                const float* xp = x0 + (((size_t)b * 512 + gy) * 512 + gx) * 32 + qq * 8;
                v0 = *(const float4*)xp;
                v1 = *(const float4*)(xp + 4);
            }
            *(short8*)&lds[X0_E + qq * X0_KS + pix * 8] = pack8(v0, v1);
        }
    }
    __syncthreads();                                   // (1)

    // ================= conv1: h1(16x16x64), A from global =================
    {
        floatx4 acc[4][4];
#pragma unroll
        for (int mi = 0; mi < 4; ++mi) {
            float4 bb = *(const float4*)&B1[mi * 16 + q * 4];   // bias as C-init
            floatx4 ib = (floatx4){bb.x, bb.y, bb.z, bb.w};
#pragma unroll
            for (int n = 0; n < 4; ++n) acc[mi][n] = ib;
        }
        const int wsel = q * 512 + m * 8;
        short8 Anow[4];
#pragma unroll
        for (int mi = 0; mi < 4; ++mi)
            Anow[mi] = *(const short8*)&W1t[wsel + mi * 128];

        for (int tap = 0; tap < 9; ++tap) {
            int tn = tap < 8 ? tap + 1 : 8;
            short8 Anext[4];
#pragma unroll
            for (int mi = 0; mi < 4; ++mi)
                Anext[mi] = *(const short8*)&W1t[tn * 2048 + wsel + mi * 128];
            int dy = tap / 3, dx = tap - dy * 3;
            short8 Bx[4];
#pragma unroll
            for (int n = 0; n < 4; ++n) {
                int ptile = n * 4 + wave;
                Bx[n] = *(const short8*)&lds[X0_E + q * X0_KS + ((ptile + dy) * 18 + (m + dx)) * 8];
            }
#pragma unroll
            for (int mi = 0; mi < 4; ++mi)
#pragma unroll
                for (int n = 0; n < 4; ++n)
                    acc[mi][n] = __builtin_amdgcn_mfma_f32_16x16x32_bf16(Anow[mi], Bx[n], acc[mi][n], 0, 0, 0);
#pragma unroll
            for (int mi = 0; mi < 4; ++mi) Anow[mi] = Anext[mi];
        }
        // epilogue: relu (+mask on edge) -> h1, packed b64 stores
        if (!edge) {
#pragma unroll
            for (int mi = 0; mi < 4; ++mi) {
                int ks = mi * 2 + (q >> 1), lo = (q & 1) * 4;
#pragma unroll
                for (int n = 0; n < 4; ++n) {
                    int ptile = n * 4 + wave;
                    floatx4 a = acc[mi][n];
                    *(short4v*)&lds[H1_E + ks * H1_KS + (ptile * 16 + m) * 8 + lo] =
                        pack4(fmaxf(a[0], 0.f), fmaxf(a[1], 0.f), fmaxf(a[2], 0.f), fmaxf(a[3], 0.f));
                }
            }
        } else {
#pragma unroll
            for (int mi = 0; mi < 4; ++mi) {
                int ks = mi * 2 + (q >> 1), lo = (q & 1) * 4;
#pragma unroll
                for (int n = 0; n < 4; ++n) {
                    int ptile = n * 4 + wave;
                    int gy = ty0 - 2 + ptile, gx = tx0 - 2 + m;
                    bool ok = ((uint_t)gy < 512u) && ((uint_t)gx < 512u);
                    floatx4 a = acc[mi][n];
                    float v0 = ok ? fmaxf(a[0], 0.f) : 0.f;
                    float v1 = ok ? fmaxf(a[1], 0.f) : 0.f;
                    float v2 = ok ? fmaxf(a[2], 0.f) : 0.f;
                    float v3 = ok ? fmaxf(a[3], 0.f) : 0.f;
                    *(short4v*)&lds[H1_E + ks * H1_KS + (ptile * 16 + m) * 8 + lo] = pack4(v0, v1, v2, v3);
                }
            }
        }
    }
    __syncthreads();                                   // (2)

    // ================= conv2: h2(14x14x64), A from global =================
    {
        floatx4 acc[4][4];
#pragma unroll
        for (int mi = 0; mi < 4; ++mi) {
            float4 bb = *(const float4*)&B2[mi * 16 + q * 4];
            floatx4 ib = (floatx4){bb.x, bb.y, bb.z, bb.w};
#pragma unroll
            for (int n = 0; n < 4; ++n) acc[mi][n] = ib;
        }
        int hb2[4];
#pragma unroll
        for (int n = 0; n < 4; ++n) {
            int p0 = (n * 4 + wave) * 16 + m;
            int pv = p0 < 196 ? p0 : 195;              // clamp unused tiles in-range
            int py = pv / 14, px = pv - py * 14;
            hb2[n] = py * 16 + px;
        }
        const int wsel = q * 512 + m * 8;
        short8 Anow[4];
#pragma unroll
        for (int mi = 0; mi < 4; ++mi)
            Anow[mi] = *(const short8*)&W2t[wsel + mi * 128];

        for (int s = 0; s < 18; ++s) {
            int tap = s >> 1, kh = s & 1;
            int sn = s < 17 ? s + 1 : 17;
            short8 Anext[4];
#pragma unroll
            for (int mi = 0; mi < 4; ++mi)
                Anext[mi] = *(const short8*)&W2t[(sn >> 1) * 4096 + ((sn & 1) * 4) * 512 + wsel + mi * 128];
            int dy = tap / 3, dx = tap - dy * 3;
            short8 Bx[4];
#pragma unroll
            for (int n = 0; n < 4; ++n)
                Bx[n] = *(const short8*)&lds[H1_E + (kh * 4 + q) * H1_KS + (hb2[n] + dy * 16 + dx) * 8];
#pragma unroll
            for (int mi = 0; mi < 4; ++mi)
#pragma unroll
                for (int n = 0; n < 4; ++n) {
                    int ptile = n * 4 + wave;
                    if (ptile < 13)
                        acc[mi][n] = __builtin_amdgcn_mfma_f32_16x16x32_bf16(Anow[mi], Bx[n], acc[mi][n], 0, 0, 0);
                }
#pragma unroll
            for (int mi = 0; mi < 4; ++mi) Anow[mi] = Anext[mi];
        }
        __syncthreads();                               // (3) drain h1 reads (h2 overlays)
        // epilogue: relu (+mask on edge) -> h2 [8 ks x 1616], packed b64
#pragma unroll
        for (int n = 0; n < 4; ++n) {
            int ptile = n * 4 + wave;
            if (ptile >= 13) continue;
            int p = ptile * 16 + m;
            bool pok = p < 196;
            bool ok = pok;
            if (edge) {
                int py = p / 14, px = p - py * 14;
                int gy = ty0 - 1 + py, gx = tx0 - 1 + px;
                ok = pok && ((uint_t)gy < 512u) && ((uint_t)gx < 512u);
            }
#pragma unroll
            for (int mi = 0; mi < 4; ++mi) {
                int ks = mi * 2 + (q >> 1), lo = (q & 1) * 4;
                floatx4 a = acc[mi][n];
                float v0 = ok ? fmaxf(a[0], 0.f) : 0.f;
                float v1 = ok ? fmaxf(a[1], 0.f) : 0.f;
                float v2 = ok ? fmaxf(a[2], 0.f) : 0.f;
                float v3 = ok ? fmaxf(a[3], 0.f) : 0.f;
                if (pok)
                    *(short4v*)&lds[H2_E + ks * H2_KS + p * 8 + lo] = pack4(v0, v1, v2, v3);
            }
        }
    }
    __syncthreads();                                   // (4)

    // ========== conv3 via MFMA: A (selected W3) from global ==========
    {
        floatx4 acc3[9];
#pragma unroll
        for (int n = 0; n < 9; ++n) acc3[n] = (floatx4){0.f, 0.f, 0.f, 0.f};
        int hb3[9];
#pragma unroll
        for (int n = 0; n < 9; ++n) {
            int p = n * 16 + m;
            int pv = p < 144 ? p : 143;
            int py = pv / 12, px = pv - py * 12;
            hb3[n] = py * 14 + px;
        }
        const ushort_t* W3c = W3T + cls * 9216;
        for (int t2 = wave; t2 < 18; t2 += 4) {
            int tap = t2 >> 1, kh = t2 & 1;
            int dy = tap / 3, dx = tap - dy * 3;
            short8 Aw = *(const short8*)&W3c[t2 * 512 + q * 128 + m * 8];
#pragma unroll
            for (int n = 0; n < 9; ++n) {
                short8 Bh = *(const short8*)&lds[H2_E + (kh * 4 + q) * H2_KS + (hb3[n] + dy * 14 + dx) * 8];
                acc3[n] = __builtin_amdgcn_mfma_f32_16x16x32_bf16(Aw, Bh, acc3[n], 0, 0, 0);
            }
        }
        float* sf = ldsf + SF_F;
        if (q == 0) {
#pragma unroll
            for (int n = 0; n < 9; ++n) {
                float2 v = {acc3[n][0], acc3[n][1]};
                *(float2*)&sf[wave * 288 + n * 32 + m * 2] = v;
            }
        }
    }
    __syncthreads();                                   // (5)
    if (t < 144) {
        float* sf = ldsf + SF_F;
        int p = t;
        int base = (p >> 4) * 32 + (p & 15) * 2;
        float a0 = sf[base] + sf[288 + base] + sf[576 + base] + sf[864 + base];
        int py = p / 12, px = p - py * 12;
        int gy = ty0 + py, gx = tx0 + px;
        if (gy < 512 && gx < 512) {
            size_t ob = (((size_t)b * 512 + gy) * 512 + gx) * NCH;
            outp[ob] = a0 + B3[cls * NCH + 0];
            if (NCH == 2) {
                float a1 = sf[base + 1] + sf[288 + base + 1] + sf[576 + base + 1] + sf[864 + base + 1];
                outp[ob + 1] = a1 + B3[cls * NCH + 1];
            }
        }
    }
}

extern "C" void kernel_launch(void* const* d_in, const int* in_sizes, int n_in,
                              void* d_out, int out_size, void* d_ws, size_t ws_size,
                              hipStream_t stream) {
    const float* x0  = (const float*)d_in[0];
    const float* f4  = (const float*)d_in[1];
    const float* Wo1 = (const float*)d_in[2];  const float* bo1 = (const float*)d_in[3];
    const float* Wo2 = (const float*)d_in[4];  const float* bo2 = (const float*)d_in[5];
    const float* Wo3 = (const float*)d_in[6];  const float* bo3 = (const float*)d_in[7];
    const float* Ww1 = (const float*)d_in[8];  const float* bw1 = (const float*)d_in[9];
    const float* Ww2 = (const float*)d_in[10]; const float* bw2 = (const float*)d_in[11];
    const float* Ww3 = (const float*)d_in[12]; const float* bw3 = (const float*)d_in[13];
    const float* Wc1 = (const float*)d_in[14]; const float* bc1 = (const float*)d_in[15];
    const float* Wc2 = (const float*)d_in[16]; const float* bc2 = (const float*)d_in[17];
    const float* Wc3 = (const float*)d_in[18]; const float* bc3 = (const float*)d_in[19];

    float* out = (float*)d_out;
    float* offsets_out = out;                      // (4,512,512,2)
    float* weights_out = out + 2097152;            // (4,512,512,1)
    float* pred_out    = out + 3145728;            // (4,3)

    int* cls_ws = (int*)d_ws;                              // 16 B
    ushort_t* wt  = (ushort_t*)((char*)d_ws + 16);         // 110592 ushorts
    ushort_t* w3t = (ushort_t*)((char*)d_ws + 221200);     // 2x27648 ushorts
    float* gap_part = (float*)((char*)d_ws + 331792);      // 4x8x256 floats

    const ushort_t* W1o_t = wt;
    const ushort_t* W2o_t = wt + 18432;
    const ushort_t* W1w_t = wt + 55296;
    const ushort_t* W2w_t = wt + 73728;

    prep_all<<<680, 256, 0, stream>>>(Wo1, Wo2, Ww1, Ww2, Wo3, Ww3, wt, w3t, f4, gap_part);
    cls_finish<<<4, 256, 0, stream>>>(gap_part, Wc1, bc1, Wc2, bc2, Wc3, bc3, pred_out, cls_ws);

    // 232 chunks x 16 (8 tiles x 2 z) = 3712 >= 1849*2; y = batch
    dim3 grid(3712, 4);
    fused_branch<<<grid, 256, 0, stream>>>(x0,
                                           W1o_t, W2o_t, W1w_t, W2w_t, w3t,
                                           bo1, bo2, bw1, bw2,
                                           bo3, bw3,
                                           cls_ws, offsets_out, weights_out);
}

// Round 10
// 639.788 us; speedup vs baseline: 1.5871x; 1.1310x over previous
//
#include <hip/hip_runtime.h>
#include <hip/hip_bf16.h>
#include <math.h>

typedef __attribute__((ext_vector_type(8))) short short8;
typedef __attribute__((ext_vector_type(4))) short short4v;
typedef __attribute__((ext_vector_type(4))) float floatx4;
typedef unsigned short ushort_t;
typedef unsigned int uint_t;

__device__ __forceinline__ ushort_t f2bf(float x) {   // RNE f32 -> bf16
    uint_t u = __float_as_uint(x);
    uint_t r = (u + 0x7fffu + ((u >> 16) & 1u)) >> 16;
    return (ushort_t)r;
}
// HW-packed RNE conversion: 2 floats -> packed bf16x2 (v_cvt_pk_bf16_f32)
__device__ __forceinline__ short4v pack4(float a, float b, float c, float d) {
    union { __hip_bfloat162 h; uint_t u; } lo, hi;
    lo.h = __float22bfloat162_rn(make_float2(a, b));
    hi.h = __float22bfloat162_rn(make_float2(c, d));
    short4v r;
    r[0] = (short)(lo.u & 0xffffu); r[1] = (short)(lo.u >> 16);
    r[2] = (short)(hi.u & 0xffffu); r[3] = (short)(hi.u >> 16);
    return r;
}
__device__ __forceinline__ short8 pack8(float4 v0, float4 v1) {
    short4v lo = pack4(v0.x, v0.y, v0.z, v0.w);
    short4v hi = pack4(v1.x, v1.y, v1.z, v1.w);
    short8 pk;
    pk[0] = lo[0]; pk[1] = lo[1]; pk[2] = lo[2]; pk[3] = lo[3];
    pk[4] = hi[0]; pk[5] = hi[1]; pk[6] = hi[2]; pk[7] = hi[3];
    return pk;
}

// ---------------- prep: weight tiling + W3 tiling + FULL classifier -------
// 1024-thread blocks. No inter-block dependencies -> single kernel.
// blocks [0,108):   W1/W2 bf16 MFMA tiles [tap][ci/8][64 co][8 ci]
// blocks [108,162): W3 tiles [branch][cls][18 t2][4 q][16 ch][8 j]
// blocks [162,166): per-batch GAP + MLP + softmax + argmax
__global__ __launch_bounds__(1024)
void prep_all(const float* __restrict__ W1a, const float* __restrict__ W2a,
              const float* __restrict__ W1b, const float* __restrict__ W2b,
              const float* __restrict__ W3a, const float* __restrict__ W3b,
              ushort_t* __restrict__ wt, ushort_t* __restrict__ w3t,
              const float* __restrict__ f4,
              const float* __restrict__ Wc1, const float* __restrict__ bc1,
              const float* __restrict__ Wc2, const float* __restrict__ bc2,
              const float* __restrict__ Wc3, const float* __restrict__ bc3,
              float* __restrict__ pred_out, int* __restrict__ cls_out) {
    int bi = blockIdx.x, t = threadIdx.x;
    if (bi < 108) {
        int i = bi * 1024 + t;                 // [0, 110592)
        const float* W; int off; int C;
        if (i < 18432)      { W = W1a; off = i;         C = 32; }
        else if (i < 55296) { W = W2a; off = i - 18432; C = 64; }
        else if (i < 73728) { W = W1b; off = i - 55296; C = 32; }
        else                { W = W2b; off = i - 73728; C = 64; }
        int pt = C * 64;
        int tap = off / pt, rem = off - tap * pt;
        int k4 = rem >> 9, rem2 = rem & 511;
        int co = rem2 >> 3, j = rem2 & 7;
        int ci = k4 * 8 + j;
        wt[i] = f2bf(W[(size_t)(tap * C + ci) * 64 + co]);
    } else if (bi < 162) {
        int i = (bi - 108) * 1024 + t;         // [0, 55296)
        int branch = i / 27648; int r = i - branch * 27648;
        int cls = r / 9216; int r2 = r - cls * 9216;
        int t2 = r2 >> 9; int r3 = r2 & 511;
        int qq = r3 >> 7; int r4 = r3 & 127;
        int ch = r4 >> 3; int j = r4 & 7;
        int tap = t2 >> 1, kh = t2 & 1;
        int ci = kh * 32 + qq * 8 + j;
        int NCH = branch ? 1 : 2, C3 = branch ? 3 : 6;
        const float* W3 = branch ? W3b : W3a;
        ushort_t v = 0;
        if (ch < NCH) v = f2bf(W3[(size_t)(tap * 64 + ci) * C3 + cls * NCH + ch]);
        w3t[i] = v;
    } else {
        // -------- classifier for batch b, fully inside one block ----------
        int b = bi - 162;
        __shared__ float4 part4[1024];
        __shared__ float gap[256];
        __shared__ float z1[128];
        __shared__ float z2[128];
        __shared__ float lg[3];
        const float* f = f4 + (size_t)b * 1024 * 256;
        int ci4 = t & 63, po = t >> 6;         // 64 float4-groups x 16 partitions
        float4 s = {0, 0, 0, 0};
        for (int p = po; p < 1024; p += 16) {
            float4 v = *(const float4*)&f[(size_t)p * 256 + ci4 * 4];
            s.x += v.x; s.y += v.y; s.z += v.z; s.w += v.w;
        }
        part4[po * 64 + ci4] = s;
        __syncthreads();
        if (t < 64) {
            float4 g = {0, 0, 0, 0};
            for (int p = 0; p < 16; ++p) {
                float4 v = part4[p * 64 + t];
                g.x += v.x; g.y += v.y; g.z += v.z; g.w += v.w;
            }
            gap[t * 4 + 0] = g.x * (1.0f / 1024.0f);
            gap[t * 4 + 1] = g.y * (1.0f / 1024.0f);
            gap[t * 4 + 2] = g.z * (1.0f / 1024.0f);
            gap[t * 4 + 3] = g.w * (1.0f / 1024.0f);
        }
        __syncthreads();
        if (t < 128) {
            float a = bc1[t];
            for (int i = 0; i < 256; ++i) a += gap[i] * Wc1[i * 128 + t];
            z1[t] = fmaxf(a, 0.f);
        }
        __syncthreads();
        if (t < 128) {
            float a = bc2[t];
            for (int i = 0; i < 128; ++i) a += z1[i] * Wc2[i * 128 + t];
            z2[t] = fmaxf(a, 0.f);
        }
        __syncthreads();
        if (t < 3) {
            float a = bc3[t];
            for (int i = 0; i < 128; ++i) a += z2[i] * Wc3[i * 3 + t];
            lg[t] = a;
        }
        __syncthreads();
        if (t == 0) {
            float m = fmaxf(lg[0], fmaxf(lg[1], lg[2]));
            float e0 = expf(lg[0] - m), e1 = expf(lg[1] - m), e2 = expf(lg[2] - m);
            float ssum = e0 + e1 + e2;
            pred_out[b * 3 + 0] = e0 / ssum;
            pred_out[b * 3 + 1] = e1 / ssum;
            pred_out[b * 3 + 2] = e2 / ssum;
            int idx = 0; float best = lg[0];
            if (lg[1] > best) { best = lg[1]; idx = 1; }
            if (lg[2] > best) { best = lg[2]; idx = 2; }
            cls_out[b] = idx;
        }
    }
}

// ---------------- fused MFMA conv branch -----------------------------------
// z (branch) folded into blockIdx.x so blocks i and i+8 share a tile on the
// SAME XCD (round-robin i%8) -> second x0 fetch hits L2 (FETCH halved, R9).
// A = weights from global (pre-tiled); B = pixels in LDS.
// LDS (ushort) -- total 26880 ushorts = 53760 B EXACTLY (3 blocks/CU; R9's
// 54272 B crossed the cliff to 2 blocks/CU and cost 24%):
//   x0  [4 ks x 2608]   : [0, 10432)
//   h1  [8 ks x 2056]   : [10432, 26880)
//   h2  [8 ks x 1616]   : [0, 12928)   overlays x0+h1-head (barrier-protected)
//   SF  1152 floats     : floats [6464, 7616) = ushort [12928, 15232)
#define X0_E 0
#define X0_KS 2608
#define H1_E 10432
#define H1_KS 2056
#define H2_E 0
#define H2_KS 1616
#define SF_F 6464
#define LDS_E 26880

__global__ __launch_bounds__(256, 3)
void fused_branch(const float* __restrict__ x0,
                  const ushort_t* __restrict__ W1o_t, const ushort_t* __restrict__ W2o_t,
                  const ushort_t* __restrict__ W1w_t, const ushort_t* __restrict__ W2w_t,
                  const ushort_t* __restrict__ w3t,
                  const float* __restrict__ bo1, const float* __restrict__ bo2,
                  const float* __restrict__ bw1, const float* __restrict__ bw2,
                  const float* __restrict__ bo3, const float* __restrict__ bw3,
                  const int* __restrict__ clsp,
                  float* __restrict__ off_out, float* __restrict__ w_out) {
    __shared__ __align__(16) ushort_t lds[LDS_E];
    float* ldsf = (float*)lds;
    const int t = threadIdx.x;
    const int b = blockIdx.y;
    // pair mapping: chunk of 16 blocks covers 8 tiles x 2 z on one XCD pass
    const int u = blockIdx.x;
    const int slot = u & 15;
    const int z = slot >> 3;
    const int tix = (u >> 4) * 8 + (slot & 7);
    if (tix >= 1849) return;
    const ushort_t* W1t = z ? W1w_t : W1o_t;
    const ushort_t* W2t = z ? W2w_t : W2o_t;
    const ushort_t* W3T = w3t + z * 27648;
    const float* B1 = z ? bw1 : bo1;
    const float* B2 = z ? bw2 : bo2;
    const float* B3 = z ? bw3 : bo3;
    float* outp = z ? w_out : off_out;
    const int NCH = z ? 1 : 2;

    const int tileY = tix / 43, tileX = tix - tileY * 43;
    const int ty0 = tileY * 12, tx0 = tileX * 12;
    const bool edge = (tileY == 0) | (tileY == 42) | (tileX == 0) | (tileX == 42);
    const int lane = t & 63, wave = t >> 6;
    const int m = lane & 15, q = lane >> 4;
    const int cls = clsp[b];

    // ---- stage x0 (18x18x32 fp32 -> bf16 [4 ks][324 px][8]) ----
    if (!edge) {
        for (int idx = t; idx < 1296; idx += 256) {
            int pix = idx >> 2, qq = idx & 3;
            int py = pix / 18, px = pix - py * 18;
            const float* xp = x0 + (((size_t)b * 512 + (ty0 - 3 + py)) * 512 + (tx0 - 3 + px)) * 32 + qq * 8;
            *(short8*)&lds[X0_E + qq * X0_KS + pix * 8] =
                pack8(*(const float4*)xp, *(const float4*)(xp + 4));
        }
    } else {
        for (int idx = t; idx < 1296; idx += 256) {
            int pix = idx >> 2, qq = idx & 3;
            int py = pix / 18, px = pix - py * 18;
            int gy = ty0 - 3 + py, gx = tx0 - 3 + px;
            float4 v0 = {0, 0, 0, 0}, v1 = {0, 0, 0, 0};
            if ((uint_t)gy < 512u && (uint_t)gx < 512u) {
                const float* xp = x0 + (((size_t)b * 512 + gy) * 512 + gx) * 32 + qq * 8;
                v0 = *(const float4*)xp;
                v1 = *(const float4*)(xp + 4);
            }
            *(short8*)&lds[X0_E + qq * X0_KS + pix * 8] = pack8(v0, v1);
        }
    }
    __syncthreads();                                   // (1)

    // ================= conv1: h1(16x16x64), A from global =================
    {
        floatx4 acc[4][4];
#pragma unroll
        for (int mi = 0; mi < 4; ++mi) {
            float4 bb = *(const float4*)&B1[mi * 16 + q * 4];   // bias as C-init
            floatx4 ib = (floatx4){bb.x, bb.y, bb.z, bb.w};
#pragma unroll
            for (int n = 0; n < 4; ++n) acc[mi][n] = ib;
        }
        const int wsel = q * 512 + m * 8;
        short8 Anow[4];
#pragma unroll
        for (int mi = 0; mi < 4; ++mi)
            Anow[mi] = *(const short8*)&W1t[wsel + mi * 128];

        for (int tap = 0; tap < 9; ++tap) {
            int tn = tap < 8 ? tap + 1 : 8;
            short8 Anext[4];
#pragma unroll
            for (int mi = 0; mi < 4; ++mi)
                Anext[mi] = *(const short8*)&W1t[tn * 2048 + wsel + mi * 128];
            int dy = tap / 3, dx = tap - dy * 3;
            short8 Bx[4];
#pragma unroll
            for (int n = 0; n < 4; ++n) {
                int ptile = n * 4 + wave;
                Bx[n] = *(const short8*)&lds[X0_E + q * X0_KS + ((ptile + dy) * 18 + (m + dx)) * 8];
            }
#pragma unroll
            for (int mi = 0; mi < 4; ++mi)
#pragma unroll
                for (int n = 0; n < 4; ++n)
                    acc[mi][n] = __builtin_amdgcn_mfma_f32_16x16x32_bf16(Anow[mi], Bx[n], acc[mi][n], 0, 0, 0);
#pragma unroll
            for (int mi = 0; mi < 4; ++mi) Anow[mi] = Anext[mi];
        }
        // epilogue: relu (+mask on edge) -> h1, packed b64 stores
        if (!edge) {
#pragma unroll
            for (int mi = 0; mi < 4; ++mi) {
                int ks = mi * 2 + (q >> 1), lo = (q & 1) * 4;
#pragma unroll
                for (int n = 0; n < 4; ++n) {
                    int ptile = n * 4 + wave;
                    floatx4 a = acc[mi][n];
                    *(short4v*)&lds[H1_E + ks * H1_KS + (ptile * 16 + m) * 8 + lo] =
                        pack4(fmaxf(a[0], 0.f), fmaxf(a[1], 0.f), fmaxf(a[2], 0.f), fmaxf(a[3], 0.f));
                }
            }
        } else {
#pragma unroll
            for (int mi = 0; mi < 4; ++mi) {
                int ks = mi * 2 + (q >> 1), lo = (q & 1) * 4;
#pragma unroll
                for (int n = 0; n < 4; ++n) {
                    int ptile = n * 4 + wave;
                    int gy = ty0 - 2 + ptile, gx = tx0 - 2 + m;
                    bool ok = ((uint_t)gy < 512u) && ((uint_t)gx < 512u);
                    floatx4 a = acc[mi][n];
                    float v0 = ok ? fmaxf(a[0], 0.f) : 0.f;
                    float v1 = ok ? fmaxf(a[1], 0.f) : 0.f;
                    float v2 = ok ? fmaxf(a[2], 0.f) : 0.f;
                    float v3 = ok ? fmaxf(a[3], 0.f) : 0.f;
                    *(short4v*)&lds[H1_E + ks * H1_KS + (ptile * 16 + m) * 8 + lo] = pack4(v0, v1, v2, v3);
                }
            }
        }
    }
    __syncthreads();                                   // (2)

    // ================= conv2: h2(14x14x64), A from global =================
    {
        floatx4 acc[4][4];
#pragma unroll
        for (int mi = 0; mi < 4; ++mi) {
            float4 bb = *(const float4*)&B2[mi * 16 + q * 4];
            floatx4 ib = (floatx4){bb.x, bb.y, bb.z, bb.w};
#pragma unroll
            for (int n = 0; n < 4; ++n) acc[mi][n] = ib;
        }
        int hb2[4];
#pragma unroll
        for (int n = 0; n < 4; ++n) {
            int p0 = (n * 4 + wave) * 16 + m;
            int pv = p0 < 196 ? p0 : 195;              // clamp unused tiles in-range
            int py = pv / 14, px = pv - py * 14;
            hb2[n] = py * 16 + px;
        }
        const int wsel = q * 512 + m * 8;
        short8 Anow[4];
#pragma unroll
        for (int mi = 0; mi < 4; ++mi)
            Anow[mi] = *(const short8*)&W2t[wsel + mi * 128];

        for (int s = 0; s < 18; ++s) {
            int tap = s >> 1, kh = s & 1;
            int sn = s < 17 ? s + 1 : 17;
            short8 Anext[4];
#pragma unroll
            for (int mi = 0; mi < 4; ++mi)
                Anext[mi] = *(const short8*)&W2t[(sn >> 1) * 4096 + ((sn & 1) * 4) * 512 + wsel + mi * 128];
            int dy = tap / 3, dx = tap - dy * 3;
            short8 Bx[4];
#pragma unroll
            for (int n = 0; n < 4; ++n)
                Bx[n] = *(const short8*)&lds[H1_E + (kh * 4 + q) * H1_KS + (hb2[n] + dy * 16 + dx) * 8];
#pragma unroll
            for (int mi = 0; mi < 4; ++mi)
#pragma unroll
                for (int n = 0; n < 4; ++n) {
                    int ptile = n * 4 + wave;
                    if (ptile < 13)
                        acc[mi][n] = __builtin_amdgcn_mfma_f32_16x16x32_bf16(Anow[mi], Bx[n], acc[mi][n], 0, 0, 0);
                }
#pragma unroll
            for (int mi = 0; mi < 4; ++mi) Anow[mi] = Anext[mi];
        }
        __syncthreads();                               // (3) drain h1 reads (h2 overlays)
        // epilogue: relu (+mask on edge) -> h2 [8 ks x 1616], packed b64
#pragma unroll
        for (int n = 0; n < 4; ++n) {
            int ptile = n * 4 + wave;
            if (ptile >= 13) continue;
            int p = ptile * 16 + m;
            bool pok = p < 196;
            bool ok = pok;
            if (edge) {
                int py = p / 14, px = p - py * 14;
                int gy = ty0 - 1 + py, gx = tx0 - 1 + px;
                ok = pok && ((uint_t)gy < 512u) && ((uint_t)gx < 512u);
            }
#pragma unroll
            for (int mi = 0; mi < 4; ++mi) {
                int ks = mi * 2 + (q >> 1), lo = (q & 1) * 4;
                floatx4 a = acc[mi][n];
                float v0 = ok ? fmaxf(a[0], 0.f) : 0.f;
                float v1 = ok ? fmaxf(a[1], 0.f) : 0.f;
                float v2 = ok ? fmaxf(a[2], 0.f) : 0.f;
                float v3 = ok ? fmaxf(a[3], 0.f) : 0.f;
                if (pok)
                    *(short4v*)&lds[H2_E + ks * H2_KS + p * 8 + lo] = pack4(v0, v1, v2, v3);
            }
        }
    }
    __syncthreads();                                   // (4)

    // ========== conv3 via MFMA: A (selected W3) from global ==========
    {
        floatx4 acc3[9];
#pragma unroll
        for (int n = 0; n < 9; ++n) acc3[n] = (floatx4){0.f, 0.f, 0.f, 0.f};
        int hb3[9];
#pragma unroll
        for (int n = 0; n < 9; ++n) {
            int p = n * 16 + m;
            int pv = p < 144 ? p : 143;
            int py = pv / 12, px = pv - py * 12;
            hb3[n] = py * 14 + px;
        }
        const ushort_t* W3c = W3T + cls * 9216;
        for (int t2 = wave; t2 < 18; t2 += 4) {
            int tap = t2 >> 1, kh = t2 & 1;
            int dy = tap / 3, dx = tap - dy * 3;
            short8 Aw = *(const short8*)&W3c[t2 * 512 + q * 128 + m * 8];
#pragma unroll
            for (int n = 0; n < 9; ++n) {
                short8 Bh = *(const short8*)&lds[H2_E + (kh * 4 + q) * H2_KS + (hb3[n] + dy * 14 + dx) * 8];
                acc3[n] = __builtin_amdgcn_mfma_f32_16x16x32_bf16(Aw, Bh, acc3[n], 0, 0, 0);
            }
        }
        float* sf = ldsf + SF_F;
        if (q == 0) {
#pragma unroll
            for (int n = 0; n < 9; ++n) {
                float2 v = {acc3[n][0], acc3[n][1]};
                *(float2*)&sf[wave * 288 + n * 32 + m * 2] = v;
            }
        }
    }
    __syncthreads();                                   // (5)
    if (t < 144) {
        float* sf = ldsf + SF_F;
        int p = t;
        int base = (p >> 4) * 32 + (p & 15) * 2;
        float a0 = sf[base] + sf[288 + base] + sf[576 + base] + sf[864 + base];
        int py = p / 12, px = p - py * 12;
        int gy = ty0 + py, gx = tx0 + px;
        if (gy < 512 && gx < 512) {
            size_t ob = (((size_t)b * 512 + gy) * 512 + gx) * NCH;
            outp[ob] = a0 + B3[cls * NCH + 0];
            if (NCH == 2) {
                float a1 = sf[base + 1] + sf[288 + base + 1] + sf[576 + base + 1] + sf[864 + base + 1];
                outp[ob + 1] = a1 + B3[cls * NCH + 1];
            }
        }
    }
}

extern "C" void kernel_launch(void* const* d_in, const int* in_sizes, int n_in,
                              void* d_out, int out_size, void* d_ws, size_t ws_size,
                              hipStream_t stream) {
    const float* x0  = (const float*)d_in[0];
    const float* f4  = (const float*)d_in[1];
    const float* Wo1 = (const float*)d_in[2];  const float* bo1 = (const float*)d_in[3];
    const float* Wo2 = (const float*)d_in[4];  const float* bo2 = (const float*)d_in[5];
    const float* Wo3 = (const float*)d_in[6];  const float* bo3 = (const float*)d_in[7];
    const float* Ww1 = (const float*)d_in[8];  const float* bw1 = (const float*)d_in[9];
    const float* Ww2 = (const float*)d_in[10]; const float* bw2 = (const float*)d_in[11];
    const float* Ww3 = (const float*)d_in[12]; const float* bw3 = (const float*)d_in[13];
    const float* Wc1 = (const float*)d_in[14]; const float* bc1 = (const float*)d_in[15];
    const float* Wc2 = (const float*)d_in[16]; const float* bc2 = (const float*)d_in[17];
    const float* Wc3 = (const float*)d_in[18]; const float* bc3 = (const float*)d_in[19];

    float* out = (float*)d_out;
    float* offsets_out = out;                      // (4,512,512,2)
    float* weights_out = out + 2097152;            // (4,512,512,1)
    float* pred_out    = out + 3145728;            // (4,3)

    int* cls_ws = (int*)d_ws;                              // 16 B
    ushort_t* wt  = (ushort_t*)((char*)d_ws + 16);         // 110592 ushorts
    ushort_t* w3t = (ushort_t*)((char*)d_ws + 221200);     // 2x27648 ushorts

    const ushort_t* W1o_t = wt;
    const ushort_t* W2o_t = wt + 18432;
    const ushort_t* W1w_t = wt + 55296;
    const ushort_t* W2w_t = wt + 73728;

    prep_all<<<166, 1024, 0, stream>>>(Wo1, Wo2, Ww1, Ww2, Wo3, Ww3, wt, w3t, f4,
                                       Wc1, bc1, Wc2, bc2, Wc3, bc3,
                                       pred_out, cls_ws);

    // 232 chunks x 16 (8 tiles x 2 z) = 3712 >= 1849*2; y = batch
    dim3 grid(3712, 4);
    fused_branch<<<grid, 256, 0, stream>>>(x0,
                                           W1o_t, W2o_t, W1w_t, W2w_t, w3t,
                                           bo1, bo2, bw1, bw2,
                                           bo3, bw3,
                                           cls_ws, offsets_out, weights_out);
}